// Round 4
// baseline (272.000 us; speedup 1.0000x reference)
//
#include <hip/hip_runtime.h>
#include <stdint.h>

typedef unsigned short u16;
typedef __bf16 bf16x8 __attribute__((ext_vector_type(8)));
typedef short s16x4 __attribute__((ext_vector_type(4)));
typedef float f32x4 __attribute__((ext_vector_type(4)));

#define QKV_STRIDE 12288    // per (s,h): 384 * 32

__device__ __forceinline__ u16 f2bf(float x) {
    unsigned int u = __float_as_uint(x);
    u += 0x7fffu + ((u >> 16) & 1u);
    return (u16)(u >> 16);
}
__device__ __forceinline__ float bf2f(u16 h) {
    return __uint_as_float(((unsigned int)h) << 16);
}

// async global->LDS, 16B per lane; lds dest must be wave-uniform base + lane*16
__device__ __forceinline__ void async_copy16(const u16* g, u16* l) {
    __builtin_amdgcn_global_load_lds(
        (const __attribute__((address_space(1))) unsigned int*)g,
        (__attribute__((address_space(3))) unsigned int*)l, 16, 0, 0);
}

// PV matmul: 16x16x16 bf16 (P^T C-frag is directly a valid B-frag).
static __device__ __forceinline__ f32x4 pv_mfma(s16x4 a, s16x4 b, f32x4 c) {
#if __has_builtin(__builtin_amdgcn_mfma_f32_16x16x16bf16_1k)
    return __builtin_amdgcn_mfma_f32_16x16x16bf16_1k(a, b, c, 0, 0, 0);
#else
    union { s16x4 h[2]; bf16x8 v; } ua, ub;
    s16x4 zz = {0, 0, 0, 0};
    ua.h[0] = a; ua.h[1] = zz;
    ub.h[0] = b; ub.h[1] = zz;
    return __builtin_amdgcn_mfma_f32_16x16x32_bf16(ua.v, ub.v, c, 0, 0, 0);
#endif
}

// ------------------------------------------------- prep: convert msa + pack W
__global__ void prep(const float* __restrict__ msa,
                     const float* __restrict__ Wq, const float* __restrict__ Wk,
                     const float* __restrict__ Wv, const float* __restrict__ Wo,
                     u16* __restrict__ msa_bf, u16* __restrict__ Wqkv,
                     u16* __restrict__ Woh, u16* __restrict__ Wol) {
    int b = blockIdx.x;
    if (b < 12288) {
        int i = b * 256 + threadIdx.x;
        float4 v = ((const float4*)msa)[i];
        ushort4 o;
        o.x = f2bf(v.x); o.y = f2bf(v.y); o.z = f2bf(v.z); o.w = f2bf(v.w);
        ((ushort4*)msa_bf)[i] = o;
    } else {
        int i = (b - 12288) * 256 + threadIdx.x;     // 65536 total
        Wqkv[i]          = f2bf(Wq[i]);
        Wqkv[65536 + i]  = f2bf(Wk[i]);
        Wqkv[131072 + i] = f2bf(Wv[i]);
        float w = Wo[i];
        u16 hi = f2bf(w);
        Woh[i] = hi;
        Wol[i] = f2bf(w - bf2f(hi));
    }
}

// ---------------------------------------------------------------- QKV GEMM
// A (msa) staged to LDS via global_load_lds with XOR-swizzled 16B chunks
// (conflict-free frag reads, BK=64). B (W, 384 KB, L2-resident) read directly
// from global as b128 frags. tn<4: transposed orientation (Q,K packed stores,
// Q pre-scaled by SCALE*log2e). tn>=4: normal orientation, V^T stores.
__launch_bounds__(256, 2)
__global__ void qkv_gemm(const u16* __restrict__ A, const u16* __restrict__ W,
                         u16* __restrict__ Qb, u16* __restrict__ Kb, u16* __restrict__ VTb) {
    __shared__ __align__(16) u16 As[128 * 64];   // 16 KB, swizzled chunks
    const int tid = threadIdx.x;
    const int tm = blockIdx.x % 384, tn = blockIdx.x / 384;   // grid 2304
    const bool trans = (tn < 4);
    const int lane = tid & 63, wave = tid >> 6;
    const int lm = lane & 15, lq = lane >> 4;
    const int lm7 = lm & 7;
    const int wm = (wave >> 1) * 64, wn = (wave & 1) * 64;
    const float CEXPF = 0.17677669529663687f * 1.4426950408889634f;
    f32x4 acc[4][4] = {};

    // staging: copy j covers rows j*32 + wave*8 + (lane>>3); lane fetches the
    // swizzled chunk (lane&7)^(lane>>3) so LDS dest stays lane-contiguous.
    const int srow = wave * 8 + (lane >> 3);
    const int schunk = (lane & 7) ^ (lane >> 3);
    u16* ldsd[4]; const u16* gsrc[4];
    #pragma unroll
    for (int j = 0; j < 4; ++j) {
        ldsd[j] = &As[j * 2048 + wave * 512 + lane * 8];
        gsrc[j] = &A[(tm * 128 + j * 32 + srow) * 256 + schunk * 8];
    }
    const int rbm = trans ? wn : wm;               // LDS (msa) frag row base
    const int rbg = tn * 128 + (trans ? wm : wn);  // global (W) frag row base

    for (int k0 = 0; k0 < 256; k0 += 64) {
        #pragma unroll
        for (int j = 0; j < 4; ++j) async_copy16(gsrc[j] + k0, ldsd[j]);
        // W frags direct from global (L2-resident)
        bf16x8 wf[4][2];
        #pragma unroll
        for (int x = 0; x < 4; ++x)
            #pragma unroll
            for (int kk = 0; kk < 2; ++kk)
                wf[x][kk] = *(const bf16x8*)&W[(rbg + x * 16 + lm) * 256 + k0 + kk * 32 + lq * 8];
        __syncthreads();
        bf16x8 mf[4][2];
        #pragma unroll
        for (int x = 0; x < 4; ++x)
            #pragma unroll
            for (int kk = 0; kk < 2; ++kk)
                mf[x][kk] = *(const bf16x8*)&As[(rbm + x * 16 + lm) * 64 + ((kk * 4 + lq) ^ lm7) * 8];
        #pragma unroll
        for (int kk = 0; kk < 2; ++kk)
            #pragma unroll
            for (int i = 0; i < 4; ++i)
                #pragma unroll
                for (int j = 0; j < 4; ++j)
                    acc[i][j] = __builtin_amdgcn_mfma_f32_16x16x32_bf16(
                        trans ? wf[i][kk] : mf[i][kk],
                        trans ? mf[j][kk] : wf[j][kk], acc[i][j], 0, 0, 0);
        __syncthreads();
    }

    if (trans) {
        // m = feature F (r -> d contiguous), n = msa row R
        #pragma unroll
        for (int i = 0; i < 4; ++i) {
            int F0 = tn * 128 + wm + i * 16 + lq * 4;
            int which = F0 >> 8;                 // 0=Q, 1=K
            int h = (F0 >> 5) & 7, d0 = F0 & 31;
            u16* dst = which ? Kb : Qb;
            float scale = which ? 1.0f : CEXPF;
            #pragma unroll
            for (int j = 0; j < 4; ++j) {
                int R = tm * 128 + wn + j * 16 + lm;
                int s = R / 384, l = R - s * 384;
                ushort4 o;
                o.x = f2bf(acc[i][j][0] * scale);
                o.y = f2bf(acc[i][j][1] * scale);
                o.z = f2bf(acc[i][j][2] * scale);
                o.w = f2bf(acc[i][j][3] * scale);
                *(ushort4*)&dst[((s * 8 + h) * 384 + l) * 32 + d0] = o;
            }
        }
    } else {
        // m = msa row R (r -> l contiguous), n = feature F in [512,768)
        #pragma unroll
        for (int j = 0; j < 4; ++j) {
            int F = tn * 128 + wn + j * 16 + lm;
            int h = (F >> 5) & 7, d = F & 31;
            #pragma unroll
            for (int i = 0; i < 4; ++i) {
                int R0 = tm * 128 + wm + i * 16 + lq * 4;
                int s = R0 / 384, l0 = R0 - s * 384;
                ushort4 o;
                o.x = f2bf(acc[i][j][0]);
                o.y = f2bf(acc[i][j][1]);
                o.z = f2bf(acc[i][j][2]);
                o.w = f2bf(acc[i][j][3]);
                *(ushort4*)&VTb[((s * 8 + h) * 32 + d) * 384 + l0] = o;
            }
        }
    }
}

// ---------------------------------------------------------------- attention
// Grid 3072: block = (s,h, l-part of 128). V^T in LDS; K direct from global
// (L2-resident) with one-tile software prefetch. S^T = K*Q^T feeds 16x16x16
// PV directly from registers; l = 1^T*P via ones-MFMA. Writes Ahi only.
__launch_bounds__(256, 4)
__global__ void msa_attention(const u16* __restrict__ Qb, const u16* __restrict__ Kb,
                              const u16* __restrict__ VTb, u16* __restrict__ Ahi) {
    __shared__ __align__(16) u16 Vt[32 * 392];   // 25088 B (V^T rows, stride 392)
    const int tid = threadIdx.x;
    const int bid = blockIdx.x;                   // 3072 blocks
    const int sh = bid / 3, lpart = bid - sh * 3;
    const int s = sh >> 3, h = sh & 7;
    const u16* Qg = Qb + (size_t)sh * QKV_STRIDE;
    const u16* Kg = Kb + (size_t)sh * QKV_STRIDE;
    const u16* Vg = VTb + (size_t)sh * QKV_STRIDE;

    for (int i = tid; i < 1536; i += 256) {
        int d = i / 48, c = i - d * 48;
        *(uint4*)&Vt[d * 392 + c * 8] = *(const uint4*)&Vg[d * 384 + c * 8];
    }

    const int lane = tid & 63, wave = tid >> 6;
    const int lm = lane & 15, lq = lane >> 4;

    bf16x8 aq[2];
    #pragma unroll
    for (int it = 0; it < 2; ++it) {
        int l = lpart * 128 + (wave * 2 + it) * 16 + lm;
        aq[it] = *(const bf16x8*)&Qg[l * 32 + lq * 8];
    }

    // prefetch K tile 0 (global; independent of the Vt barrier)
    bf16x8 kf0[2], kf1[2];
    kf0[0] = *(const bf16x8*)&Kg[lm * 32 + lq * 8];
    kf1[0] = *(const bf16x8*)&Kg[(16 + lm) * 32 + lq * 8];
    __syncthreads();
    s16x4 vf[2][4];
    vf[0][0] = *(const s16x4*)&Vt[lm * 392 + lq * 4];
    vf[0][1] = *(const s16x4*)&Vt[lm * 392 + 16 + lq * 4];
    vf[0][2] = *(const s16x4*)&Vt[(16 + lm) * 392 + lq * 4];
    vf[0][3] = *(const s16x4*)&Vt[(16 + lm) * 392 + 16 + lq * 4];

    f32x4 o[2][2] = {};
    f32x4 lacc[2] = {};
    const s16x4 ones = {(short)0x3F80, (short)0x3F80, (short)0x3F80, (short)0x3F80};

    #pragma unroll
    for (int t = 0; t < 12; ++t) {
        const int cur = t & 1, nxt = cur ^ 1;
        if (t < 11) {                      // prefetch tile t+1
            const int nn = (t + 1) * 32;
            kf0[nxt] = *(const bf16x8*)&Kg[(nn + lm) * 32 + lq * 8];
            kf1[nxt] = *(const bf16x8*)&Kg[(nn + 16 + lm) * 32 + lq * 8];
            vf[nxt][0] = *(const s16x4*)&Vt[lm * 392 + nn + lq * 4];
            vf[nxt][1] = *(const s16x4*)&Vt[lm * 392 + nn + 16 + lq * 4];
            vf[nxt][2] = *(const s16x4*)&Vt[(16 + lm) * 392 + nn + lq * 4];
            vf[nxt][3] = *(const s16x4*)&Vt[(16 + lm) * 392 + nn + 16 + lq * 4];
        }
        #pragma unroll
        for (int it = 0; it < 2; ++it) {
            f32x4 z = {0.f, 0.f, 0.f, 0.f};
            f32x4 s0 = __builtin_amdgcn_mfma_f32_16x16x32_bf16(kf0[cur], aq[it], z, 0, 0, 0);
            f32x4 s1 = __builtin_amdgcn_mfma_f32_16x16x32_bf16(kf1[cur], aq[it], z, 0, 0, 0);
            float p0[4], p1[4];
            #pragma unroll
            for (int r = 0; r < 4; ++r) {
                p0[r] = __builtin_amdgcn_exp2f(s0[r]);
                p1[r] = __builtin_amdgcn_exp2f(s1[r]);
            }
            union { s16x4 v; uint2 u; } pk0, pk1;
            pk0.u.x = __builtin_amdgcn_perm(__float_as_uint(p0[1]), __float_as_uint(p0[0]), 0x07060302u);
            pk0.u.y = __builtin_amdgcn_perm(__float_as_uint(p0[3]), __float_as_uint(p0[2]), 0x07060302u);
            pk1.u.x = __builtin_amdgcn_perm(__float_as_uint(p1[1]), __float_as_uint(p1[0]), 0x07060302u);
            pk1.u.y = __builtin_amdgcn_perm(__float_as_uint(p1[3]), __float_as_uint(p1[2]), 0x07060302u);
            o[it][0] = pv_mfma(vf[cur][0], pk0.v, o[it][0]);
            o[it][0] = pv_mfma(vf[cur][1], pk1.v, o[it][0]);
            o[it][1] = pv_mfma(vf[cur][2], pk0.v, o[it][1]);
            o[it][1] = pv_mfma(vf[cur][3], pk1.v, o[it][1]);
            lacc[it] = pv_mfma(ones, pk0.v, lacc[it]);
            lacc[it] = pv_mfma(ones, pk1.v, lacc[it]);
        }
    }

    #pragma unroll
    for (int it = 0; it < 2; ++it) {
        float inv = __builtin_amdgcn_rcpf(lacc[it][0]);
        int l = lpart * 128 + (wave * 2 + it) * 16 + lm;
        int base = (s * 384 + l) * 256 + h * 32 + lq * 4;
        #pragma unroll
        for (int dt = 0; dt < 2; ++dt) {
            ushort4 oh;
            oh.x = f2bf(o[it][dt][0] * inv);
            oh.y = f2bf(o[it][dt][1] * inv);
            oh.z = f2bf(o[it][dt][2] * inv);
            oh.w = f2bf(o[it][dt][3] * inv);
            *(ushort4*)&Ahi[base + dt * 16] = oh;
        }
    }
}

// ---------------------------------------------------------------- output GEMM
// out = Ah*(Wh+Wl)^T (A-rounding term dropped; predicted +3e-5 absmax).
// Ah staged to LDS (swizzled, BK=64); Woh/Wol (256 KB, L2-resident) direct.
// Transposed orientation -> float4 stores.
__launch_bounds__(256, 2)
__global__ void out_gemm(const u16* __restrict__ Ahi,
                         const u16* __restrict__ Woh, const u16* __restrict__ Wol,
                         float* __restrict__ out) {
    __shared__ __align__(16) u16 As[128 * 64];   // 16 KB
    const int tid = threadIdx.x;
    const int tm = blockIdx.x % 384, tn = blockIdx.x / 384;   // grid 768
    const int lane = tid & 63, wave = tid >> 6;
    const int lm = lane & 15, lq = lane >> 4;
    const int lm7 = lm & 7;
    const int wm = (wave >> 1) * 64, wn = (wave & 1) * 64;
    f32x4 acc[4][4] = {};

    const int srow = wave * 8 + (lane >> 3);
    const int schunk = (lane & 7) ^ (lane >> 3);
    u16* ldsd[4]; const u16* gsrc[4];
    #pragma unroll
    for (int j = 0; j < 4; ++j) {
        ldsd[j] = &As[j * 2048 + wave * 512 + lane * 8];
        gsrc[j] = &Ahi[(tm * 128 + j * 32 + srow) * 256 + schunk * 8];
    }

    for (int k0 = 0; k0 < 256; k0 += 64) {
        #pragma unroll
        for (int j = 0; j < 4; ++j) async_copy16(gsrc[j] + k0, ldsd[j]);
        bf16x8 whf[4][2], wlf[4][2];
        #pragma unroll
        for (int i = 0; i < 4; ++i)
            #pragma unroll
            for (int kk = 0; kk < 2; ++kk) {
                int off = (tn * 128 + wm + i * 16 + lm) * 256 + k0 + kk * 32 + lq * 8;
                whf[i][kk] = *(const bf16x8*)&Woh[off];
                wlf[i][kk] = *(const bf16x8*)&Wol[off];
            }
        __syncthreads();
        bf16x8 af[4][2];
        #pragma unroll
        for (int j = 0; j < 4; ++j)
            #pragma unroll
            for (int kk = 0; kk < 2; ++kk)
                af[j][kk] = *(const bf16x8*)&As[(wn + j * 16 + lm) * 64 + ((kk * 4 + lq) ^ lm7) * 8];
        #pragma unroll
        for (int kk = 0; kk < 2; ++kk)
            #pragma unroll
            for (int i = 0; i < 4; ++i)
                #pragma unroll
                for (int j = 0; j < 4; ++j) {
                    acc[i][j] = __builtin_amdgcn_mfma_f32_16x16x32_bf16(wlf[i][kk], af[j][kk], acc[i][j], 0, 0, 0);
                    acc[i][j] = __builtin_amdgcn_mfma_f32_16x16x32_bf16(whf[i][kk], af[j][kk], acc[i][j], 0, 0, 0);
                }
        __syncthreads();
    }
    #pragma unroll
    for (int i = 0; i < 4; ++i) {
        int F0 = tn * 128 + wm + i * 16 + lq * 4;
        #pragma unroll
        for (int j = 0; j < 4; ++j) {
            int R = tm * 128 + wn + j * 16 + lm;
            *(f32x4*)&out[R * 256 + F0] = acc[i][j];
        }
    }
}

// ---------------------------------------------------------------- launch
extern "C" void kernel_launch(void* const* d_in, const int* in_sizes, int n_in,
                              void* d_out, int out_size, void* d_ws, size_t ws_size,
                              hipStream_t stream) {
    const float* msa = (const float*)d_in[0];
    const float* Wq = (const float*)d_in[2];
    const float* Wk = (const float*)d_in[3];
    const float* Wv = (const float*)d_in[4];
    const float* Wo = (const float*)d_in[5];
    char* ws = (char*)d_ws;
    u16* msa_bf = (u16*)(ws + 0);              // 25165824 B
    u16* Qb     = (u16*)(ws + 25165824);       // 25165824 B  [sh][l][d], pre-scaled
    u16* Kb     = (u16*)(ws + 50331648);       // 25165824 B  [sh][l][d]
    u16* VTb    = (u16*)(ws + 75497472);       // 25165824 B  [sh][d][l]
    u16* Ahi    = (u16*)(ws + 100663296);      // 25165824 B
    u16* Wqkv   = (u16*)(ws + 150994944);      // 393216 B
    u16* Woh    = (u16*)(ws + 151388160);      // 131072 B
    u16* Wol    = (u16*)(ws + 151519232);      // 131072 B
    float* out  = (float*)d_out;

    hipLaunchKernelGGL(prep, dim3(12544), dim3(256), 0, stream, msa, Wq, Wk, Wv, Wo,
                       msa_bf, Wqkv, Woh, Wol);
    hipLaunchKernelGGL(qkv_gemm, dim3(2304), dim3(256), 0, stream, msa_bf, Wqkv, Qb, Kb, VTb);
    hipLaunchKernelGGL(msa_attention, dim3(3072), dim3(256), 0, stream, Qb, Kb, VTb, Ahi);
    hipLaunchKernelGGL(out_gemm, dim3(768), dim3(256), 0, stream, Ahi, Woh, Wol, out);
}